// Round 10
// baseline (163.470 us; speedup 1.0000x reference)
//
#include <hip/hip_runtime.h>
#include <cstdint>
#include <cstddef>

// DeepFM Criteo forward, MI355X/gfx950 — round 10 (round-6 kernel; 4 timeouts, never ran).
//   prep   : emb2->bf16; w1 -> permuted bf16 *128 (fp8 scale); w2 -> bf16
//   gemm_p : P2[f][v][h] = emb2 @ (128*w1)''^T, stored FP8 e4m3 (32 MB, L3-fit)
//   mega   : gather-sum P2 (fp8 decode, software-pipelined) -> h1 LDS
//            + FM fp32 + gemm2 MFMA + (w3/128) dot + sigmoid.

#define B_ROWS   16384
#define NSPARSE  26
#define NDENSE   13
#define EMBD     128
#define HID      256
#define K1       (NSPARSE*EMBD)   // 3328
#define VOCAB    4823
#define PAD_V    4864             // 38*128
#define NP       (NSPARSE*HID)    // 6656
#define PSCALE   128.0f
#define PINV     (1.0f/128.0f)

typedef unsigned short ushort_t;
typedef unsigned char  uchar_t;
typedef __attribute__((ext_vector_type(8))) short bf16x8;            // MFMA A/B frag
typedef __attribute__((ext_vector_type(8))) unsigned short ushort8;
typedef __attribute__((ext_vector_type(4))) float f32x4;             // MFMA C/D frag
typedef __attribute__((ext_vector_type(2))) float f32x2;

__device__ __forceinline__ ushort_t f32_bf16(float x) {
    unsigned u = __builtin_bit_cast(unsigned, x);
    u += 0x7fffu + ((u >> 16) & 1u);
    return (ushort_t)(u >> 16);
}
__device__ __forceinline__ float bf16_f32(ushort_t h) {
    return __builtin_bit_cast(float, ((unsigned)h) << 16);
}
// decode 8 fp8 (2 dwords) and accumulate into h[0..7]
__device__ __forceinline__ void dec8acc(int a, int b, float* h) {
    f32x2 r0 = __builtin_amdgcn_cvt_pk_f32_fp8(a, false);
    f32x2 r1 = __builtin_amdgcn_cvt_pk_f32_fp8(a, true);
    f32x2 r2 = __builtin_amdgcn_cvt_pk_f32_fp8(b, false);
    f32x2 r3 = __builtin_amdgcn_cvt_pk_f32_fp8(b, true);
    h[0] += r0.x; h[1] += r0.y; h[2] += r1.x; h[3] += r1.y;
    h[4] += r2.x; h[5] += r2.y; h[6] += r3.x; h[7] += r3.y;
}

// async global->LDS, 16B/lane; LDS dest = wave-uniform base + lane*16 (linear).
__device__ __forceinline__ void gl2lds16(const void* g, void* l) {
    __builtin_amdgcn_global_load_lds(
        (const __attribute__((address_space(1))) void*)g,
        (__attribute__((address_space(3))) void*)l, 16, 0, 0);
}

// ---------------------------------------------------------------------------
// prep: all fp32->bf16 conversions in one launch.
//   seg A: emb2 -> e2b                                     (straight)
//   seg B: 128*w1[h, f*128+d] -> b1b[(f*256+h)*128+d]      (permute + scale)
//   seg C: w2 -> w2b                                       (straight)
// ---------------------------------------------------------------------------
__global__ __launch_bounds__(256) void prep_kernel(
    const float* __restrict__ emb2, const float* __restrict__ w1,
    const float* __restrict__ w2, ushort_t* __restrict__ e2b,
    ushort_t* __restrict__ b1b, ushort_t* __restrict__ w2b) {
    constexpr int NA = VOCAB * EMBD / 4;   // 154336
    constexpr int NB = NP * EMBD / 4;      // 212992
    constexpr int NC = HID * HID / 4;      // 16384
    int i = blockIdx.x * 256 + threadIdx.x;
    float4 x;
    ushort_t* dst;
    int di;
    float sc = 1.f;
    if (i < NA) {
        x = ((const float4*)emb2)[i]; dst = e2b; di = i;
    } else if (i < NA + NB) {
        int j = i - NA;
        int c = j & 31, rowp = j >> 5;
        int f = rowp >> 8, h = rowp & 255;
        x = ((const float4*)w1)[h * (K1 / 4) + f * 32 + c];
        dst = b1b; di = j; sc = PSCALE;
    } else if (i < NA + NB + NC) {
        int j = i - NA - NB;
        x = ((const float4*)w2)[j]; dst = w2b; di = j;
    } else return;
    union { ushort_t u[4]; uint2 v; } H;
    float xs[4] = {x.x, x.y, x.z, x.w};
#pragma unroll
    for (int j = 0; j < 4; ++j) H.u[j] = f32_bf16(xs[j] * sc);
    ((uint2*)dst)[di] = H.v;
}

// ---------------------------------------------------------------------------
// gemm_p: P2[(f*PAD_V + v)*HID + h] = fp8( sum_d e2b[v,d] * b1b[f*256+h, d] )
// 128x128 tile, K=128 single-shot: one stage of A+B (64 KB LDS, granule-XOR
// swizzle g ^= row&7 on global source and ds_read addr), one barrier,
// 64 MFMA/wave, LDS-transpose epilogue -> coalesced 16B fp8 stores.
// ---------------------------------------------------------------------------
__global__ __launch_bounds__(256) void gemm_p_kernel(
    const ushort_t* __restrict__ A, const ushort_t* __restrict__ Bm,
    uchar_t* __restrict__ P2) {
    __shared__ union {
        struct { ushort_t a[128 * 128]; ushort_t b[128 * 128]; } s;  // 64 KB
        uchar_t t[128 * 128];                                        // 16 KB
    } sm;
    const int tid = threadIdx.x;
    const int bm = blockIdx.x, bn = blockIdx.y;
    const int lane = tid & 63, wv = tid >> 6;

    // stage: 2048 16B-slots per operand; slot s holds data granule (s&15)^(row&7)
#pragma unroll
    for (int i = 0; i < 8; ++i) {
        int s = (wv * 8 + i) * 64 + lane;
        int row = s >> 4, g = s & 15;
        int gs = g ^ (row & 7);
        gl2lds16(A  + (size_t)(bm * 128 + row) * EMBD + gs * 8, &sm.s.a[s * 8]);
        gl2lds16(Bm + (size_t)(bn * 128 + row) * EMBD + gs * 8, &sm.s.b[s * 8]);
    }
    __syncthreads();   // drains vmcnt

    const int wr = wv >> 1, wc = wv & 1;
    const int lrow = lane & 15, lq = lane >> 4;
    f32x4 acc[4][4] = {};
#pragma unroll
    for (int ks = 0; ks < 4; ++ks) {
        bf16x8 af[4], bf[4];
#pragma unroll
        for (int m = 0; m < 4; ++m) {
            int row = wr * 64 + m * 16 + lrow;
            int g = (ks * 4 + lq) ^ (row & 7);
            af[m] = *(const bf16x8*)&sm.s.a[row * 128 + g * 8];
        }
#pragma unroll
        for (int n = 0; n < 4; ++n) {
            int row = wc * 64 + n * 16 + lrow;
            int g = (ks * 4 + lq) ^ (row & 7);
            bf[n] = *(const bf16x8*)&sm.s.b[row * 128 + g * 8];
        }
#pragma unroll
        for (int m = 0; m < 4; ++m)
#pragma unroll
            for (int n = 0; n < 4; ++n)
                acc[m][n] = __builtin_amdgcn_mfma_f32_16x16x32_bf16(af[m], bf[n], acc[m][n], 0, 0, 0);
    }
    __syncthreads();   // all ds_reads done before t overwrites a[]

    // epilogue: frag (col=lane&15, row=(lane>>4)*4+reg) -> fp8 bytes in LDS
#pragma unroll
    for (int m = 0; m < 4; ++m)
#pragma unroll
        for (int n = 0; n < 4; ++n) {
            int col = wc * 64 + n * 16 + lrow;
#pragma unroll
            for (int r = 0; r < 4; ++r) {
                int row = wr * 64 + m * 16 + lq * 4 + r;
                float v = acc[m][n][r];
                int e = __builtin_amdgcn_cvt_pk_fp8_f32(v, v, 0, false);
                sm.t[row * 128 + col] = (uchar_t)(e & 0xff);
            }
        }
    __syncthreads();
    const int f0 = bn >> 1, half = bn & 1;
    const int r8 = tid >> 3, c8 = tid & 7;   // 32 rows/pass, 8 threads/row * 16B
#pragma unroll
    for (int k = 0; k < 4; ++k) {
        int row = k * 32 + r8;
        int4 v16 = *(const int4*)&sm.t[row * 128 + c8 * 16];
        *(int4*)&P2[((size_t)f0 * PAD_V + bm * 128 + row) * HID + half * 128 + c8 * 16] = v16;
    }
}

// ---------------------------------------------------------------------------
// mega: 16 rows per block (grid 1024). Thread (row=tid>>4, h16=tid&15).
//  A: P-gather loop (fp8, 16B/iter, fully unrolled -> deep MLP)
//  B: FM loop (bf16 e2b, separate loop so each pipeline is load-dominated)
//  C: h1 -> LDS bf16 [16][264]; gemm2 MFMA (A from LDS, B=w2b from L2)
//  D: y3 = (w3/128) . relu(h2_scaled); out = sigmoid(y12 + y3)
// ---------------------------------------------------------------------------
#define H1LD 264
__global__ __launch_bounds__(256, 4) void mega_kernel(
    const uchar_t* __restrict__ P2, const ushort_t* __restrict__ e2b,
    const ushort_t* __restrict__ w2b, const float* __restrict__ dense,
    const int* __restrict__ sidx, const float* __restrict__ emb1,
    const float* __restrict__ fm_w, const float* __restrict__ w3,
    float* __restrict__ out) {
    __shared__ int      sI[16 * NSPARSE];
    __shared__ ushort_t h1s[16 * H1LD];
    __shared__ float    y12s[16];
    __shared__ float    y3s[4][16];

    const int tid = threadIdx.x;
    const int b0 = blockIdx.x * 16;
    for (int i = tid; i < 16 * NSPARSE; i += 256) sI[i] = sidx[b0 * NSPARSE + i];
    __syncthreads();

    const int row = tid >> 4, h16 = tid & 15;
    const int* rI = sI + row * NSPARSE;

    // ---- A: P2 gather (hacc = 128 * h1_pre) ----
    float hacc[16] = {};
#pragma unroll
    for (int f = 0; f < NSPARSE; ++f) {
        int v = rI[f];
        int4 q = *(const int4*)(P2 + ((size_t)f * PAD_V + v) * HID + h16 * 16);
        dec8acc(q.x, q.y, &hacc[0]);
        dec8acc(q.z, q.w, &hacc[8]);
    }
    // ---- B: FM sums (fp32 arithmetic on bf16 emb2) ----
    float s8[8] = {};
    float ss = 0.f;
#pragma unroll
    for (int f = 0; f < NSPARSE; ++f) {
        int v = rI[f];
        ushort8 ev = *(const ushort8*)(e2b + (size_t)v * EMBD + h16 * 8);
#pragma unroll
        for (int j = 0; j < 8; ++j) {
            float e = bf16_f32(ev[j]);
            s8[j] += e; ss += e * e;
        }
    }
    // h1 -> LDS (relu, bf16, scaled by 128)
    {
        union { ushort_t u[8]; ushort8 v; } o0, o1;
#pragma unroll
        for (int j = 0; j < 8; ++j) {
            o0.u[j] = f32_bf16(fmaxf(hacc[j], 0.f));
            o1.u[j] = f32_bf16(fmaxf(hacc[8 + j], 0.f));
        }
        *(ushort8*)&h1s[row * H1LD + h16 * 16]     = o0.v;
        *(ushort8*)&h1s[row * H1LD + h16 * 16 + 8] = o1.v;
    }
    // FM: y2 = 0.5*(sum_d s^2 - ss); y1 = dense.fm_w + sum emb1 (reduce over h16)
    float part = 0.f;
#pragma unroll
    for (int j = 0; j < 8; ++j) part += s8[j] * s8[j];
    part = 0.5f * (part - ss);
    if (h16 < NDENSE) {
        part += dense[(b0 + row) * NDENSE + h16] * fm_w[h16];
        part += emb1[rI[h16]] + emb1[rI[13 + h16]];
    }
#pragma unroll
    for (int o = 8; o; o >>= 1) part += __shfl_xor(part, o, 64);
    if (h16 == 0) y12s[row] = part;
    __syncthreads();

    // ---- C: gemm2 (h2_scaled = relu(W2 . h1_scaled)) ----
    const int lane = tid & 63, wv = tid >> 6;
    const int lrow = lane & 15, lq = lane >> 4;
    f32x4 acc[4] = {};
#pragma unroll
    for (int ks = 0; ks < 8; ++ks) {
        bf16x8 af = *(const bf16x8*)&h1s[lrow * H1LD + ks * 32 + lq * 8];
#pragma unroll
        for (int nt = 0; nt < 4; ++nt) {
            bf16x8 bf = *(const bf16x8*)&w2b[(size_t)(wv * 64 + nt * 16 + lrow) * HID + ks * 32 + lq * 8];
            acc[nt] = __builtin_amdgcn_mfma_f32_16x16x32_bf16(af, bf, acc[nt], 0, 0, 0);
        }
    }
    // ---- D: y3 (fold 1/128) ----
    float y3p[4] = {};
#pragma unroll
    for (int nt = 0; nt < 4; ++nt) {
        float wv3 = w3[wv * 64 + nt * 16 + lrow] * PINV;
#pragma unroll
        for (int r = 0; r < 4; ++r) y3p[r] += fmaxf(acc[nt][r], 0.f) * wv3;
    }
#pragma unroll
    for (int r = 0; r < 4; ++r)
#pragma unroll
        for (int o = 8; o; o >>= 1) y3p[r] += __shfl_xor(y3p[r], o, 64);
    if (lrow == 0)
#pragma unroll
        for (int r = 0; r < 4; ++r) y3s[wv][lq * 4 + r] = y3p[r];
    __syncthreads();
    if (tid < 16) {
        float z = y12s[tid] + y3s[0][tid] + y3s[1][tid] + y3s[2][tid] + y3s[3][tid];
        out[b0 + tid] = 1.f / (1.f + __expf(-z));
    }
}

// ---------------------------------------------------------------------------
extern "C" void kernel_launch(void* const* d_in, const int* in_sizes, int n_in,
                              void* d_out, int out_size, void* d_ws, size_t ws_size,
                              hipStream_t stream) {
    const float* dense = (const float*)d_in[0];
    const int*   sidx  = (const int*)d_in[1];
    const float* emb1  = (const float*)d_in[2];
    const float* emb2  = (const float*)d_in[3];
    const float* fm_w  = (const float*)d_in[4];
    const float* w1    = (const float*)d_in[5];
    const float* w2    = (const float*)d_in[6];
    const float* w3    = (const float*)d_in[7];
    float* out = (float*)d_out;

    // workspace carve (256B-aligned), ~35 MB
    char* p = (char*)d_ws;
    auto carve = [&](size_t bytes) { void* r = (void*)p; p += (bytes + 255) & ~(size_t)255; return r; };
    ushort_t* e2b = (ushort_t*)carve((size_t)PAD_V * EMBD * 2);
    ushort_t* b1b = (ushort_t*)carve((size_t)NP * EMBD * 2);
    ushort_t* w2b = (ushort_t*)carve((size_t)HID * HID * 2);
    uchar_t*  P2  = (uchar_t*)carve((size_t)NSPARSE * PAD_V * HID);

    constexpr int NPREP = (VOCAB * EMBD + NP * EMBD + HID * HID) / 4;  // 383712
    prep_kernel<<<(NPREP + 255) / 256, 256, 0, stream>>>(emb2, w1, w2, e2b, b1b, w2b);

    gemm_p_kernel<<<dim3(PAD_V / 128, NP / 128), 256, 0, stream>>>(e2b, b1b, P2);

    mega_kernel<<<B_ROWS / 16, 256, 0, stream>>>(
        P2, e2b, w2b, dense, sidx, emb1, fm_w, w3, out);
}